// Round 1
// baseline (430.831 us; speedup 1.0000x reference)
//
#include <hip/hip_runtime.h>
#include <hip/hip_bf16.h>
#include <math.h>

// Problem constants: x [8, 96, 256, 256] fp32, window 16x16 -> 2048 windows.
#define NWIN 2048

typedef __bf16 v8bf __attribute__((ext_vector_type(8)));
typedef __bf16 v2bf __attribute__((ext_vector_type(2)));
typedef float  v4f  __attribute__((ext_vector_type(4)));

// Kernel 1: per-window alpha = 1 + sigmoid(SE(pool(real_conv))) where
// pool(real_conv)[o] = sum_c Wr[o,c] * x_win[c,0,0]/16 + b_r[o].
// Block 2048 computes the global beta vector from b_imag.
__global__ __launch_bounds__(128) void se_alpha_kernel(
    const float* __restrict__ x,
    const float* __restrict__ w_real, const float* __restrict__ b_real,
    const float* __restrict__ car_w1, const float* __restrict__ car_b1,
    const float* __restrict__ car_w2, const float* __restrict__ car_b2,
    const float* __restrict__ b_imag,
    const float* __restrict__ cai_w1, const float* __restrict__ cai_b1,
    const float* __restrict__ cai_w2, const float* __restrict__ cai_b2,
    float* __restrict__ alpha, float* __restrict__ beta)
{
    __shared__ float wr_s[96 * 97];   // +1 pad: lane-varying row -> 2-way banks
    __shared__ float vec_s[96];
    __shared__ float pr_s[96];
    __shared__ float h1_s[32];
    const int t = threadIdx.x;
    const int n = blockIdx.x;

    if (n < NWIN) {
        const int b = n >> 8, wh = (n >> 4) & 15, ww = n & 15;
        for (int idx = t; idx < 96 * 96; idx += 128) {
            int o = idx / 96;
            int c = idx - o * 96;
            wr_s[o * 97 + c] = w_real[idx];
        }
        if (t < 96)
            vec_s[t] = x[(((size_t)(b * 96 + t)) * 256 + wh * 16) * 256 + ww * 16];
        __syncthreads();
        if (t < 96) {
            float acc = 0.f;
            #pragma unroll 8
            for (int c = 0; c < 96; ++c) acc += wr_s[t * 97 + c] * vec_s[c];
            pr_s[t] = acc * (1.0f / 16.0f) + b_real[t];
        }
        __syncthreads();
        if (t < 32) {
            float acc = car_b1[t];
            for (int o = 0; o < 96; ++o) acc += car_w1[t * 96 + o] * pr_s[o];
            h1_s[t] = fmaxf(acc, 0.f);
        }
        __syncthreads();
        if (t < 96) {
            float acc = car_b2[t];
            for (int j = 0; j < 32; ++j) acc += car_w2[t * 32 + j] * h1_s[j];
            alpha[n * 96 + t] = 1.f + 1.f / (1.f + __expf(-acc));
        }
    } else {
        // beta: pooled imag part is exactly b_imag (mean of Im(fft) of real x = 0)
        if (t < 32) {
            float acc = cai_b1[t];
            for (int o = 0; o < 96; ++o) acc += cai_w1[t * 96 + o] * b_imag[o];
            h1_s[t] = fmaxf(acc, 0.f);
        }
        __syncthreads();
        if (t < 96) {
            float acc = cai_b2[t];
            for (int j = 0; j < 32; ++j) acc += cai_w2[t * 32 + j] * h1_s[j];
            beta[t] = 1.f + 1.f / (1.f + __expf(-acc));
        }
    }
}

// Kernel 2: per window n:
//   out[p,o] = sum_c W1[o,c]*x[p,c] + W2[o,c]*x[flip(p),c]  (+ 16*alpha[o]*b_r[o] at p=(0,0))
//   W1 = (alpha .* Wr + beta .* Wi)/2 , W2 = (alpha .* Wr - beta .* Wi)/2
// GEMM: M=256 pixels, N=96 out-ch, K=96 in-ch via mfma_f32_16x16x32_bf16.
// LDS stride 40 (80B = 20 banks): b128 frag reads & staging writes are 2-way (free).
__global__ __launch_bounds__(256, 2) void wfca_main_kernel(
    const float* __restrict__ x,
    const float* __restrict__ w_real, const float* __restrict__ w_imag,
    const float* __restrict__ b_real,
    const float* __restrict__ alpha, const float* __restrict__ beta,
    float* __restrict__ out)
{
    __shared__ __bf16 x_lds[256 * 40];   // [pixel][chan-in-chunk]
    __shared__ __bf16 w1_lds[96 * 40];   // [out-ch][chan-in-chunk]
    __shared__ __bf16 w2_lds[96 * 40];

    const int t = threadIdx.x;
    const int nwin = blockIdx.x;
    const int b = nwin >> 8, wh = (nwin >> 4) & 15, ww = nwin & 15;
    const int lane = t & 63;
    const int wave = t >> 6;      // 0..3, handles m-tiles (rows h) wave*4..wave*4+3
    const int l16 = lane & 15;
    const int quad = lane >> 4;

    // staging decomposition
    const int sw = t & 15;        // w coordinate
    const int scp = t >> 4;       // channel pair 0..15
    const int wc = t & 31;        // weight column (chan in chunk)
    const int wo0 = t >> 5;       // 0..7

    v4f acc[4][6];
    #pragma unroll
    for (int i = 0; i < 4; ++i)
        #pragma unroll
        for (int j = 0; j < 6; ++j)
            acc[i][j] = v4f{0.f, 0.f, 0.f, 0.f};

    const size_t xbase = (((size_t)b * 96) * 256 + wh * 16) * 256 + ww * 16;

    for (int kc = 0; kc < 3; ++kc) {
        const int c0 = kc * 32;
        if (kc) __syncthreads();

        // --- stage x chunk (channels c0..c0+31) as bf16, pixel-major ---
        {
            const float* xp = x + xbase + (size_t)(c0 + 2 * scp) * 65536 + sw;
            #pragma unroll
            for (int h = 0; h < 16; ++h) {
                float f0 = xp[h * 256];
                float f1 = xp[h * 256 + 65536];
                v2bf pk;
                pk[0] = (__bf16)f0;
                pk[1] = (__bf16)f1;
                *(v2bf*)&x_lds[(h * 16 + sw) * 40 + 2 * scp] = pk;
            }
        }
        // --- stage scaled weights for this chunk ---
        {
            #pragma unroll
            for (int i = 0; i < 12; ++i) {
                int o = wo0 + 8 * i;
                float wr = w_real[o * 96 + c0 + wc];
                float wi = w_imag[o * 96 + c0 + wc];
                float a  = alpha[nwin * 96 + o];
                float bt = beta[o];
                w1_lds[o * 40 + wc] = (__bf16)(0.5f * (a * wr + bt * wi));
                w2_lds[o * 40 + wc] = (__bf16)(0.5f * (a * wr - bt * wi));
            }
        }
        __syncthreads();

        // --- compute: A frags (x and flipped-x), B frags (W1, W2) ---
        v8bf a_x[4], a_f[4];
        #pragma unroll
        for (int mi = 0; mi < 4; ++mi) {
            int h = wave * 4 + mi;
            // A[m=l16][k=quad*8+j]: pixel p = 16h + m
            a_x[mi] = *(const v8bf*)&x_lds[(h * 16 + l16) * 40 + quad * 8];
            // flipped pixel: (hf, wf) = ((16-h)&15, (16-m)&15)
            int hf = (16 - h) & 15;
            int wf = (16 - l16) & 15;
            a_f[mi] = *(const v8bf*)&x_lds[(hf * 16 + wf) * 40 + quad * 8];
        }
        #pragma unroll
        for (int n = 0; n < 6; ++n) {
            // B[k][n]: lane holds W[n_base+l16][k], 8 consecutive k
            v8bf b1 = *(const v8bf*)&w1_lds[(n * 16 + l16) * 40 + quad * 8];
            v8bf b2 = *(const v8bf*)&w2_lds[(n * 16 + l16) * 40 + quad * 8];
            #pragma unroll
            for (int mi = 0; mi < 4; ++mi) {
                acc[mi][n] = __builtin_amdgcn_mfma_f32_16x16x32_bf16(a_x[mi], b1, acc[mi][n], 0, 0, 0);
                acc[mi][n] = __builtin_amdgcn_mfma_f32_16x16x32_bf16(a_f[mi], b2, acc[mi][n], 0, 0, 0);
            }
        }
    }

    // --- epilogue: C/D layout col=l16 (out-ch), row=quad*4+r (= w coord) ---
    #pragma unroll
    for (int n = 0; n < 6; ++n) {
        int o = n * 16 + l16;
        #pragma unroll
        for (int mi = 0; mi < 4; ++mi) {
            int h = wave * 4 + mi;
            v4f v = acc[mi][n];
            if (h == 0 && quad == 0) {
                // bias delta at (0,0): IFFT of constant b_r over bins = 16*b_r at origin
                v[0] += 16.f * alpha[nwin * 96 + o] * b_real[o];
            }
            size_t idx = (((size_t)(b * 96 + o)) * 256 + wh * 16 + h) * 256 + ww * 16 + quad * 4;
            *(v4f*)(out + idx) = v;
        }
    }
}

extern "C" void kernel_launch(void* const* d_in, const int* in_sizes, int n_in,
                              void* d_out, int out_size, void* d_ws, size_t ws_size,
                              hipStream_t stream) {
    const float* x      = (const float*)d_in[0];
    const float* w_real = (const float*)d_in[1];
    const float* b_real = (const float*)d_in[2];
    const float* w_imag = (const float*)d_in[3];
    const float* b_imag = (const float*)d_in[4];
    const float* car_w1 = (const float*)d_in[5];
    const float* car_b1 = (const float*)d_in[6];
    const float* car_w2 = (const float*)d_in[7];
    const float* car_b2 = (const float*)d_in[8];
    const float* cai_w1 = (const float*)d_in[9];
    const float* cai_b1 = (const float*)d_in[10];
    const float* cai_w2 = (const float*)d_in[11];
    const float* cai_b2 = (const float*)d_in[12];
    float* out = (float*)d_out;

    float* alpha = (float*)d_ws;            // [2048*96]
    float* beta  = alpha + NWIN * 96;       // [96]

    se_alpha_kernel<<<NWIN + 1, 128, 0, stream>>>(
        x, w_real, b_real, car_w1, car_b1, car_w2, car_b2,
        b_imag, cai_w1, cai_b1, cai_w2, cai_b2, alpha, beta);

    wfca_main_kernel<<<NWIN, 256, 0, stream>>>(
        x, w_real, w_imag, b_real, alpha, beta, out);
}